// Round 2
// baseline (12994.556 us; speedup 1.0000x reference)
//
#include <hip/hip_runtime.h>
#include <hip/hip_bf16.h>

// ---- model constants ----
#define BB 16
#define TT 256
#define SS 256
#define N_AST 300
#define DD 512
#define HH 8
#define DKK 64
#define DFF 2048
#define LL 6

// =========================================================================
// Embedding + positional encoding: x[b,t,d] = emb[ids[b,t],d] + pe(t,d)
// grid: B*T blocks, 256 threads, 2 elems/thread
// =========================================================================
__global__ __launch_bounds__(256) void embed_k(const int* __restrict__ ids,
                                               const float* __restrict__ emb,
                                               float* __restrict__ x) {
    int row = blockIdx.x;          // b*T + t
    int t = row & (TT - 1);
    int id = ids[row];
    int d0 = threadIdx.x, d1 = threadIdx.x + 256;
    float e0 = emb[(size_t)id * DD + d0];
    float e1 = emb[(size_t)id * DD + d1];
    const float c = -9.210340371976184f / 512.0f;   // -ln(10000)/D
    float f0 = expf((float)(d0 & ~1) * c);
    float f1 = expf((float)(d1 & ~1) * c);
    float p0 = (d0 & 1) ? cosf(t * f0) : sinf(t * f0);
    float p1 = (d1 & 1) ? cosf(t * f1) : sinf(t * f1);
    size_t o = (size_t)row * DD;
    x[o + d0] = e0 + p0;
    x[o + d1] = e1 + p1;
}

// =========================================================================
// conv (kernel=1) over node axis, fused for ast_outputs and ast_embed:
// ast1[b,s,d] = sum_n cw[s,n]*ast_out[b,n,d] + cb[s];  same for ast_e1.
// grid: (S, B), 256 threads, 2 d per thread
// =========================================================================
__global__ __launch_bounds__(256) void conv_k(const float* __restrict__ ast_out,
                                              const float* __restrict__ ast_emb,
                                              const float* __restrict__ cw,
                                              const float* __restrict__ cb,
                                              float* __restrict__ ast1,
                                              float* __restrict__ ast_e1) {
    int s = blockIdx.x, b = blockIdx.y;
    __shared__ float w[N_AST];
    for (int i = threadIdx.x; i < N_AST; i += 256) w[i] = cw[s * N_AST + i];
    __syncthreads();
    int d0 = threadIdx.x, d1 = threadIdx.x + 256;
    float a0 = 0, a1 = 0, e0 = 0, e1 = 0;
    const float* po = ast_out + (size_t)b * N_AST * DD;
    const float* pm = ast_emb + (size_t)b * N_AST * DD;
    for (int n = 0; n < N_AST; n++) {
        float wn = w[n];
        a0 += wn * po[n * DD + d0];
        a1 += wn * po[n * DD + d1];
        e0 += wn * pm[n * DD + d0];
        e1 += wn * pm[n * DD + d1];
    }
    float bb = cb[s];
    size_t o = ((size_t)b * SS + s) * DD;
    ast1[o + d0] = a0 + bb;
    ast1[o + d1] = a1 + bb;
    ast_e1[o + d0] = e0 + bb;
    ast_e1[o + d1] = e1 + bb;
}

// =========================================================================
// mm attention: scores[b,s,t] = dot(ast1[b,s,:], enc[b,t,:])/8 -> softmax_t
// -> mm_ctx[b,s,d] = sum_t p * enc[b,t,d].  grid: (S, B), 256 threads.
// =========================================================================
__global__ __launch_bounds__(256) void mm_attn_k(const float* __restrict__ ast1,
                                                 const float* __restrict__ enc,
                                                 float* __restrict__ mm_ctx) {
    int s = blockIdx.x, b = blockIdx.y;
    __shared__ float arow[DD];
    __shared__ float red[256];
    __shared__ float p[256];
    size_t abase = ((size_t)b * SS + s) * DD;
    arow[threadIdx.x] = ast1[abase + threadIdx.x];
    arow[threadIdx.x + 256] = ast1[abase + threadIdx.x + 256];
    __syncthreads();
    int t = threadIdx.x;
    const float* erow = enc + ((size_t)b * TT + t) * DD;
    float acc = 0;
    #pragma unroll 8
    for (int k = 0; k < DD; k++) acc += arow[k] * erow[k];
    acc *= 0.125f;
    red[t] = acc; __syncthreads();
    for (int off = 128; off > 0; off >>= 1) {
        if (t < off) red[t] = fmaxf(red[t], red[t + off]);
        __syncthreads();
    }
    float mx = red[0]; __syncthreads();
    float e = __expf(acc - mx);
    red[t] = e; __syncthreads();
    for (int off = 128; off > 0; off >>= 1) {
        if (t < off) red[t] += red[t + off];
        __syncthreads();
    }
    p[t] = e / red[0];
    __syncthreads();
    float c0 = 0, c1 = 0;
    int d0 = threadIdx.x, d1 = threadIdx.x + 256;
    for (int tt = 0; tt < 256; tt++) {
        float pv = p[tt];
        const float* er = enc + ((size_t)b * TT + tt) * DD;
        c0 += pv * er[d0];
        c1 += pv * er[d1];
    }
    size_t o = ((size_t)b * SS + s) * DD;
    mm_ctx[o + d0] = c0;
    mm_ctx[o + d1] = c1;
}

// =========================================================================
// Generic fp32 GEMM  C[M,N] = A[M,K] @ W[K,N]  (+bias +res, relu)
// 64x64 tile, BK=16, 256 threads, 4x4 per thread. M%64==0, N%64==0, K%16==0.
// flags: 1=relu, 2=bias, 4=res
// =========================================================================
#define GBM 64
#define GBN 64
#define GBK 16
__global__ __launch_bounds__(256) void gemm_k(const float* __restrict__ A,
                                              const float* __restrict__ W,
                                              const float* __restrict__ bias,
                                              const float* __restrict__ res,
                                              float* __restrict__ C,
                                              int M, int N, int K, int flags) {
    __shared__ float As[GBK][GBM];
    __shared__ float Bs[GBK][GBN];
    int tid = threadIdx.x;
    int tx = tid & 15, ty = tid >> 4;
    int m0 = blockIdx.y * GBM, n0 = blockIdx.x * GBN;
    float acc[4][4] = {};
    for (int k0 = 0; k0 < K; k0 += GBK) {
        #pragma unroll
        for (int it = 0; it < 4; it++) {
            int e = tid + it * 256;
            int r = e >> 4, c = e & 15;
            As[c][r] = A[(size_t)(m0 + r) * K + k0 + c];
        }
        #pragma unroll
        for (int it = 0; it < 4; it++) {
            int e = tid + it * 256;
            int r = e >> 6, c = e & 63;
            Bs[r][c] = W[(size_t)(k0 + r) * N + n0 + c];
        }
        __syncthreads();
        #pragma unroll
        for (int kk = 0; kk < GBK; kk++) {
            float a[4], bv[4];
            #pragma unroll
            for (int i = 0; i < 4; i++) a[i] = As[kk][ty * 4 + i];
            #pragma unroll
            for (int j = 0; j < 4; j++) bv[j] = Bs[kk][tx * 4 + j];
            #pragma unroll
            for (int i = 0; i < 4; i++)
                #pragma unroll
                for (int j = 0; j < 4; j++)
                    acc[i][j] += a[i] * bv[j];
        }
        __syncthreads();
    }
    #pragma unroll
    for (int i = 0; i < 4; i++) {
        int m = m0 + ty * 4 + i;
        #pragma unroll
        for (int j = 0; j < 4; j++) {
            int n = n0 + tx * 4 + j;
            float v = acc[i][j];
            if (flags & 2) v += bias[n];
            if (flags & 4) v += res[(size_t)m * N + n];
            if (flags & 1) v = fmaxf(v, 0.f);
            C[(size_t)m * N + n] = v;
        }
    }
}

// =========================================================================
// attention scores + mask + softmax -> probs (written to d_out slice)
// grid: (T, H, B), 256 threads (one per key position). Tk==256 always.
// mode 0: self (pad on dec ids + causal), 1: enc pad mask, 2: none
// =========================================================================
__global__ __launch_bounds__(256) void attn_scores_k(const float* __restrict__ q,
                                                     const float* __restrict__ kbuf,
                                                     const int* __restrict__ seq_ids,
                                                     float* __restrict__ probs,
                                                     int mode) {
    int t = blockIdx.x, h = blockIdx.y, b = blockIdx.z;
    int s = threadIdx.x;
    __shared__ float qs[DKK];
    __shared__ float red[256];
    if (threadIdx.x < DKK)
        qs[threadIdx.x] = q[((size_t)b * TT + t) * DD + h * DKK + threadIdx.x];
    __syncthreads();
    const float* krow = kbuf + ((size_t)b * 256 + s) * DD + h * DKK;
    float acc = 0;
    #pragma unroll
    for (int i = 0; i < DKK; i++) acc += qs[i] * krow[i];
    acc *= 0.125f;   // 1/sqrt(64)
    bool masked = false;
    if (mode == 0)      masked = (seq_ids[b * TT + s] == 0) || (s > t);
    else if (mode == 1) masked = (seq_ids[b * SS + s] == 0);
    float sc = masked ? -1e9f : acc;
    red[s] = sc; __syncthreads();
    for (int off = 128; off > 0; off >>= 1) {
        if (s < off) red[s] = fmaxf(red[s], red[s + off]);
        __syncthreads();
    }
    float mx = red[0]; __syncthreads();
    float e = __expf(sc - mx);
    red[s] = e; __syncthreads();
    for (int off = 128; off > 0; off >>= 1) {
        if (s < off) red[s] += red[s + off];
        __syncthreads();
    }
    probs[(((size_t)b * HH + h) * TT + t) * 256 + s] = e / red[0];
}

// =========================================================================
// ctx[b,t,h*64+dk] = sum_s probs[b,h,t,s] * v[b,s,h*64+dk]
// grid: (T, B), 512 threads (one per d)
// =========================================================================
__global__ __launch_bounds__(512) void attn_ctx_k(const float* __restrict__ probs,
                                                  const float* __restrict__ vbuf,
                                                  float* __restrict__ ctx) {
    int t = blockIdx.x, b = blockIdx.y;
    int d = threadIdx.x;
    __shared__ float ps[HH][256];
    #pragma unroll
    for (int it = 0; it < 4; it++) {
        int e = threadIdx.x + it * 512;
        int hh = e >> 8, ss2 = e & 255;
        ps[hh][ss2] = probs[(((size_t)b * HH + hh) * TT + t) * 256 + ss2];
    }
    __syncthreads();
    int h = d >> 6;
    float acc = 0;
    for (int s = 0; s < 256; s++)
        acc += ps[h][s] * vbuf[((size_t)b * 256 + s) * DD + d];
    ctx[((size_t)b * TT + t) * DD + d] = acc;
}

// =========================================================================
// LayerNorm over D=512 (biased var, eps 1e-5). g/b nullable (=> 1/0).
// grid: B*T, 256 threads, 2 elems/thread.
// =========================================================================
__global__ __launch_bounds__(256) void ln_k(const float* __restrict__ in,
                                            const float* __restrict__ g,
                                            const float* __restrict__ bt,
                                            float* __restrict__ out) {
    int row = blockIdx.x;
    const float* x = in + (size_t)row * DD;
    int i0 = threadIdx.x, i1 = threadIdx.x + 256;
    float v0 = x[i0], v1 = x[i1];
    __shared__ float red[256];
    red[i0] = v0 + v1; __syncthreads();
    for (int off = 128; off > 0; off >>= 1) {
        if (i0 < off) red[i0] += red[i0 + off];
        __syncthreads();
    }
    float mu = red[0] * (1.0f / DD); __syncthreads();
    float d0 = v0 - mu, d1 = v1 - mu;
    red[i0] = d0 * d0 + d1 * d1; __syncthreads();
    for (int off = 128; off > 0; off >>= 1) {
        if (i0 < off) red[i0] += red[i0 + off];
        __syncthreads();
    }
    float rstd = rsqrtf(red[0] * (1.0f / DD) + 1e-5f);
    float g0 = g ? g[i0] : 1.f, g1 = g ? g[i1] : 1.f;
    float b0 = bt ? bt[i0] : 0.f, b1 = bt ? bt[i1] : 0.f;
    size_t o = (size_t)row * DD;
    out[o + i0] = d0 * rstd * g0 + b0;
    out[o + i1] = d1 * rstd * g1 + b1;
}

// =========================================================================
// host orchestration
// =========================================================================
static inline void launch_gemm(const float* A, const float* W, const float* bias,
                               const float* res, float* C, int M, int N, int K,
                               int flags, hipStream_t stream) {
    dim3 grid(N / GBN, M / GBM);
    gemm_k<<<grid, 256, 0, stream>>>(A, W, bias, res, C, M, N, K, flags);
}

extern "C" void kernel_launch(void* const* d_in, const int* in_sizes, int n_in,
                              void* d_out, int out_size, void* d_ws, size_t ws_size,
                              hipStream_t stream) {
    const int*   dec_inputs  = (const int*)  d_in[0];
    const int*   enc_inputs  = (const int*)  d_in[1];
    const float* enc_outputs = (const float*)d_in[2];
    const float* ast_outputs = (const float*)d_in[3];
    const float* src_embed   = (const float*)d_in[4];
    const float* ast_embed   = (const float*)d_in[5];
    // d_in[6] = match_rela (unused by reference)
    const float* emb         = (const float*)d_in[7];
    const float* attn_W      = (const float*)d_in[8];
    const float* attn_ln_g   = (const float*)d_in[9];
    const float* attn_ln_b   = (const float*)d_in[10];
    const float* ffn_W1      = (const float*)d_in[11];
    const float* ffn_W2      = (const float*)d_in[12];
    const float* conv_w      = (const float*)d_in[13];
    const float* conv_b      = (const float*)d_in[14];
    const float* multi_ffn_W = (const float*)d_in[15];
    const float* multi_ffn_b = (const float*)d_in[16];

    const size_t NTD = (size_t)BB * TT * DD;        // 2,097,152
    const size_t ATT = (size_t)BB * HH * TT * 256;  // 8,388,608 per layer/type

    float* out_x    = (float*)d_out;
    float* out_self = out_x + NTD;
    float* out_enc  = out_self + (size_t)LL * ATT;
    float* out_ast  = out_enc + (size_t)LL * ATT;

    float* ws  = (float*)d_ws;
    float* xb  = ws;            // [B*T, D]
    float* tmp = xb  + NTD;
    float* qb  = tmp + NTD;
    float* kb  = qb  + NTD;
    float* vb  = kb  + NTD;
    float* cb  = vb  + NTD;
    float* mo  = cb  + NTD;     // multi_out, persists across layers
    float* hb  = mo  + NTD;     // [B*T, DFF]

    const int M = BB * TT;      // 4096

    // ---- embedding + PE ----
    embed_k<<<BB * TT, 256, 0, stream>>>(dec_inputs, emb, xb);

    // ---- Multi_model front-end ----
    conv_k<<<dim3(SS, BB), 256, 0, stream>>>(ast_outputs, ast_embed, conv_w, conv_b,
                                             qb /*ast1*/, kb /*ast_e1*/);
    mm_attn_k<<<dim3(SS, BB), 256, 0, stream>>>(qb, enc_outputs, vb /*mm_ctx*/);
    // multi_out = src_embed @ W_top + bias + mm_ctx, then += ast_e1 @ W_bot
    launch_gemm(src_embed, multi_ffn_W, multi_ffn_b, vb, mo, M, DD, DD, 2 | 4, stream);
    launch_gemm(kb, multi_ffn_W + (size_t)DD * DD, nullptr, mo, mo, M, DD, DD, 4, stream);

    // ---- decoder layers ----
    for (int l = 0; l < LL; l++) {
        const float* Wl = attn_W + (size_t)l * 3 * 4 * DD * DD;
        for (int a = 0; a < 3; a++) {
            const float* Wq = Wl + (size_t)a * 4 * DD * DD;
            const float* Wk = Wq + (size_t)DD * DD;
            const float* Wv = Wk + (size_t)DD * DD;
            const float* Wo = Wv + (size_t)DD * DD;
            const float* g  = attn_ln_g + ((size_t)l * 3 + a) * DD;
            const float* be = attn_ln_b + ((size_t)l * 3 + a) * DD;
            const float* kvsrc = (a == 0) ? xb : (a == 1) ? enc_outputs : mo;
            float* probs = ((a == 0) ? out_self : (a == 1) ? out_enc : out_ast) + (size_t)l * ATT;
            int mode = (a == 0) ? 0 : (a == 1) ? 1 : 2;
            const int* ids = (a == 0) ? dec_inputs : enc_inputs;

            launch_gemm(xb, Wq, nullptr, nullptr, qb, M, DD, DD, 0, stream);
            launch_gemm(kvsrc, Wk, nullptr, nullptr, kb, M, DD, DD, 0, stream);
            launch_gemm(kvsrc, Wv, nullptr, nullptr, vb, M, DD, DD, 0, stream);
            attn_scores_k<<<dim3(TT, HH, BB), 256, 0, stream>>>(qb, kb, ids, probs, mode);
            attn_ctx_k<<<dim3(TT, BB), 512, 0, stream>>>(probs, vb, cb);
            launch_gemm(cb, Wo, nullptr, xb, tmp, M, DD, DD, 4, stream);
            ln_k<<<BB * TT, 256, 0, stream>>>(tmp, g, be, xb);
        }
        // FFN
        launch_gemm(xb, ffn_W1 + (size_t)l * DD * DFF, nullptr, nullptr, hb,
                    M, DFF, DD, 1 /*relu*/, stream);
        launch_gemm(hb, ffn_W2 + (size_t)l * DFF * DD, nullptr, xb, tmp,
                    M, DD, DFF, 4, stream);
        float* xdst = (l == LL - 1) ? out_x : xb;
        ln_k<<<BB * TT, 256, 0, stream>>>(tmp, nullptr, nullptr, xdst);
    }
}

// Round 3
// 9257.921 us; speedup vs baseline: 1.4036x; 1.4036x over previous
//
#include <hip/hip_runtime.h>
#include <hip/hip_bf16.h>

// ---- model constants ----
#define BB 16
#define TT 256
#define SS 256
#define N_AST 300
#define DD 512
#define HH 8
#define DKK 64
#define DFF 2048
#define LL 6

typedef __attribute__((ext_vector_type(8))) short short8;
typedef __attribute__((ext_vector_type(4))) float f32x4;
typedef __hip_bfloat16 bf16;

// async global->LDS, 16B per lane. LDS dest must be wave-uniform base; data
// lands at base + lane*16. (m97 pattern, guide §5.)
__device__ __forceinline__ void llds16(const void* g, void* l) {
    __builtin_amdgcn_global_load_lds(
        (const __attribute__((address_space(1))) void*)(uintptr_t)g,
        (__attribute__((address_space(3))) void*)(uint32_t)(uintptr_t)l,
        16, 0, 0);
}

// =========================================================================
// weight transpose + fp32->bf16: dst[C,R] = bf16(src[R,C]^T). blockIdx.z = mat.
// =========================================================================
__global__ __launch_bounds__(256) void transp_k(const float* __restrict__ src,
                                                bf16* __restrict__ dst,
                                                int R, int C) {
    __shared__ float ts[32][33];
    size_t mstride = (size_t)R * C;
    src += blockIdx.z * mstride;
    dst += blockIdx.z * mstride;
    int r0 = blockIdx.y * 32, c0 = blockIdx.x * 32;
    int tx = threadIdx.x & 31, ty = threadIdx.x >> 5;   // ty: 0..7
    #pragma unroll
    for (int p = 0; p < 4; p++)
        ts[ty + p * 8][tx] = src[(size_t)(r0 + ty + p * 8) * C + c0 + tx];
    __syncthreads();
    #pragma unroll
    for (int p = 0; p < 4; p++) {
        int rt = ty + p * 8;
        dst[(size_t)(c0 + rt) * R + r0 + tx] = __float2bfloat16(ts[tx][rt]);
    }
}

// flat fp32 -> bf16 (n multiple of 1024)
__global__ __launch_bounds__(256) void cvt_k(const float* __restrict__ src,
                                             bf16* __restrict__ dst) {
    int i = (blockIdx.x * 256 + threadIdx.x) * 4;
    #pragma unroll
    for (int j = 0; j < 4; j++) dst[i + j] = __float2bfloat16(src[i + j]);
}

// src_embed [4096,512] -> Acat[:, 0:512] bf16 (Acat row stride 1024)
__global__ __launch_bounds__(256) void cat_src_k(const float* __restrict__ src,
                                                 bf16* __restrict__ acat) {
    int row = blockIdx.x;
    int d0 = threadIdx.x, d1 = threadIdx.x + 256;
    acat[(size_t)row * 1024 + d0] = __float2bfloat16(src[(size_t)row * DD + d0]);
    acat[(size_t)row * 1024 + d1] = __float2bfloat16(src[(size_t)row * DD + d1]);
}

// =========================================================================
// Embedding + positional encoding; writes fp32 (residual) + bf16 (GEMM A)
// =========================================================================
__global__ __launch_bounds__(256) void embed_k(const int* __restrict__ ids,
                                               const float* __restrict__ emb,
                                               float* __restrict__ x,
                                               bf16* __restrict__ x16) {
    int row = blockIdx.x;
    int t = row & (TT - 1);
    int id = ids[row];
    int d0 = threadIdx.x, d1 = threadIdx.x + 256;
    float e0 = emb[(size_t)id * DD + d0];
    float e1 = emb[(size_t)id * DD + d1];
    const float c = -9.210340371976184f / 512.0f;
    float f0 = expf((float)(d0 & ~1) * c);
    float f1 = expf((float)(d1 & ~1) * c);
    float p0 = (d0 & 1) ? cosf(t * f0) : sinf(t * f0);
    float p1 = (d1 & 1) ? cosf(t * f1) : sinf(t * f1);
    size_t o = (size_t)row * DD;
    float v0 = e0 + p0, v1 = e1 + p1;
    x[o + d0] = v0; x[o + d1] = v1;
    x16[o + d0] = __float2bfloat16(v0);
    x16[o + d1] = __float2bfloat16(v1);
}

// =========================================================================
// conv over node axis: ast1 fp32 (for mm_attn), ast_e1 bf16 -> Acat[:,512:]
// =========================================================================
__global__ __launch_bounds__(256) void conv_k(const float* __restrict__ ast_out,
                                              const float* __restrict__ ast_emb,
                                              const float* __restrict__ cw,
                                              const float* __restrict__ cb,
                                              float* __restrict__ ast1,
                                              bf16* __restrict__ acat) {
    int s = blockIdx.x, b = blockIdx.y;
    __shared__ float w[N_AST];
    for (int i = threadIdx.x; i < N_AST; i += 256) w[i] = cw[s * N_AST + i];
    __syncthreads();
    int d0 = threadIdx.x, d1 = threadIdx.x + 256;
    float a0 = 0, a1 = 0, e0 = 0, e1 = 0;
    const float* po = ast_out + (size_t)b * N_AST * DD;
    const float* pm = ast_emb + (size_t)b * N_AST * DD;
    for (int n = 0; n < N_AST; n++) {
        float wn = w[n];
        a0 += wn * po[n * DD + d0];
        a1 += wn * po[n * DD + d1];
        e0 += wn * pm[n * DD + d0];
        e1 += wn * pm[n * DD + d1];
    }
    float bbv = cb[s];
    size_t row = (size_t)b * SS + s;
    ast1[row * DD + d0] = a0 + bbv;
    ast1[row * DD + d1] = a1 + bbv;
    acat[row * 1024 + 512 + d0] = __float2bfloat16(e0 + bbv);
    acat[row * 1024 + 512 + d1] = __float2bfloat16(e1 + bbv);
}

// =========================================================================
// mm attention (fp32): softmax over t of ast1 . enc / 8, then ctx
// =========================================================================
__global__ __launch_bounds__(256) void mm_attn_k(const float* __restrict__ ast1,
                                                 const float* __restrict__ enc,
                                                 float* __restrict__ mm_ctx) {
    int s = blockIdx.x, b = blockIdx.y;
    __shared__ float arow[DD];
    __shared__ float red[256];
    __shared__ float p[256];
    size_t abase = ((size_t)b * SS + s) * DD;
    arow[threadIdx.x] = ast1[abase + threadIdx.x];
    arow[threadIdx.x + 256] = ast1[abase + threadIdx.x + 256];
    __syncthreads();
    int t = threadIdx.x;
    const float* erow = enc + ((size_t)b * TT + t) * DD;
    float acc = 0;
    #pragma unroll 8
    for (int k = 0; k < DD; k++) acc += arow[k] * erow[k];
    acc *= 0.125f;
    red[t] = acc; __syncthreads();
    for (int off = 128; off > 0; off >>= 1) {
        if (t < off) red[t] = fmaxf(red[t], red[t + off]);
        __syncthreads();
    }
    float mx = red[0]; __syncthreads();
    float e = __expf(acc - mx);
    red[t] = e; __syncthreads();
    for (int off = 128; off > 0; off >>= 1) {
        if (t < off) red[t] += red[t + off];
        __syncthreads();
    }
    p[t] = e / red[0];
    __syncthreads();
    float c0 = 0, c1 = 0;
    int d0 = threadIdx.x, d1 = threadIdx.x + 256;
    for (int tt = 0; tt < 256; tt++) {
        float pv = p[tt];
        const float* er = enc + ((size_t)b * TT + tt) * DD;
        c0 += pv * er[d0];
        c1 += pv * er[d1];
    }
    size_t o = ((size_t)b * SS + s) * DD;
    mm_ctx[o + d0] = c0;
    mm_ctx[o + d1] = c1;
}

// =========================================================================
// MFMA bf16 GEMM: C[M,N] = A[M,K](bf16, lda) @ Bt[N,K](bf16)^T
// tile 128x64, BK=32, 256 thr (4 waves in 2x2), 16x16x32 MFMA.
// epilogue: +bias, +res(fp32,[M,N]), relu, write Cf(fp32) and/or Ch(bf16).
// =========================================================================
__global__ __launch_bounds__(256) void gemm_bf16_k(const bf16* __restrict__ A,
                                                   const bf16* __restrict__ Bt,
                                                   const float* __restrict__ bias,
                                                   const float* __restrict__ res,
                                                   float* __restrict__ Cf,
                                                   bf16* __restrict__ Ch,
                                                   int M, int N, int K, int lda,
                                                   int relu) {
    __shared__ __align__(16) short Als[128 * 32];   // [m][k] bf16
    __shared__ __align__(16) short Bls[64 * 32];    // [n][k] bf16
    int tid = threadIdx.x;
    int w = tid >> 6, l = tid & 63;
    int wm = w >> 1, wn = w & 1;
    int m0 = blockIdx.y * 128, n0 = blockIdx.x * 64;
    const short* Ag = (const short*)A;
    const short* Bg = (const short*)Bt;

    f32x4 zero = {0.f, 0.f, 0.f, 0.f};
    f32x4 acc[4][2];
    #pragma unroll
    for (int mt = 0; mt < 4; mt++)
        #pragma unroll
        for (int nt = 0; nt < 2; nt++) acc[mt][nt] = zero;

    int lm = l & 15, lq = l >> 4;   // fragment row/col and k-quad

    for (int k0 = 0; k0 < K; k0 += 32) {
        // stage A tile 128x32 (8 KB): 2 issues x 256 lanes x 16 B
        #pragma unroll
        for (int i = 0; i < 2; i++) {
            int e = i * 256 + tid;
            const short* g = Ag + (size_t)(m0 + (e >> 2)) * lda + k0 + (e & 3) * 8;
            llds16(g, (char*)Als + (size_t)(i * 256 + w * 64) * 16);
        }
        // stage B tile 64x32 (4 KB): 1 issue
        {
            int e = tid;
            const short* g = Bg + (size_t)(n0 + (e >> 2)) * K + k0 + (e & 3) * 8;
            llds16(g, (char*)Bls + (size_t)(w * 64) * 16);
        }
        __syncthreads();
        short8 af[4], bfr[2];
        #pragma unroll
        for (int mt = 0; mt < 4; mt++)
            af[mt] = *(const short8*)&Als[(wm * 64 + mt * 16 + lm) * 32 + lq * 8];
        #pragma unroll
        for (int nt = 0; nt < 2; nt++)
            bfr[nt] = *(const short8*)&Bls[(wn * 32 + nt * 16 + lm) * 32 + lq * 8];
        #pragma unroll
        for (int mt = 0; mt < 4; mt++)
            #pragma unroll
            for (int nt = 0; nt < 2; nt++)
                acc[mt][nt] = __builtin_amdgcn_mfma_f32_16x16x32_bf16(
                    af[mt], bfr[nt], acc[mt][nt], 0, 0, 0);
        __syncthreads();
    }

    // epilogue: C/D layout col = l&15, row = (l>>4)*4 + r
    #pragma unroll
    for (int mt = 0; mt < 4; mt++) {
        #pragma unroll
        for (int nt = 0; nt < 2; nt++) {
            int col = n0 + wn * 32 + nt * 16 + lm;
            int rowb = m0 + wm * 64 + mt * 16 + lq * 4;
            float bv = bias ? bias[col] : 0.f;
            #pragma unroll
            for (int r = 0; r < 4; r++) {
                int row = rowb + r;
                float v = acc[mt][nt][r] + bv;
                if (res)  v += res[(size_t)row * N + col];
                if (relu) v = fmaxf(v, 0.f);
                if (Cf) Cf[(size_t)row * N + col] = v;
                if (Ch) Ch[(size_t)row * N + col] = __float2bfloat16(v);
            }
        }
    }
}

// =========================================================================
// attention scores + mask + softmax -> probs (fp32, straight to d_out)
// =========================================================================
__global__ __launch_bounds__(256) void attn_scores_k(const float* __restrict__ q,
                                                     const float* __restrict__ kbuf,
                                                     const int* __restrict__ seq_ids,
                                                     float* __restrict__ probs,
                                                     int mode) {
    int t = blockIdx.x, h = blockIdx.y, b = blockIdx.z;
    int s = threadIdx.x;
    __shared__ float qs[DKK];
    __shared__ float red[256];
    if (threadIdx.x < DKK)
        qs[threadIdx.x] = q[((size_t)b * TT + t) * DD + h * DKK + threadIdx.x];
    __syncthreads();
    const float* krow = kbuf + ((size_t)b * 256 + s) * DD + h * DKK;
    float acc = 0;
    #pragma unroll
    for (int i = 0; i < DKK; i++) acc += qs[i] * krow[i];
    acc *= 0.125f;
    bool masked = false;
    if (mode == 0)      masked = (seq_ids[b * TT + s] == 0) || (s > t);
    else if (mode == 1) masked = (seq_ids[b * SS + s] == 0);
    float sc = masked ? -1e9f : acc;
    red[s] = sc; __syncthreads();
    for (int off = 128; off > 0; off >>= 1) {
        if (s < off) red[s] = fmaxf(red[s], red[s + off]);
        __syncthreads();
    }
    float mx = red[0]; __syncthreads();
    float e = __expf(sc - mx);
    red[s] = e; __syncthreads();
    for (int off = 128; off > 0; off >>= 1) {
        if (s < off) red[s] += red[s + off];
        __syncthreads();
    }
    probs[(((size_t)b * HH + h) * TT + t) * 256 + s] = e / red[0];
}

// =========================================================================
// ctx[b,t,d] = sum_s probs[b,h,t,s] * v[b,s,d]   (writes bf16 for out-proj)
// =========================================================================
__global__ __launch_bounds__(512) void attn_ctx_k(const float* __restrict__ probs,
                                                  const float* __restrict__ vbuf,
                                                  bf16* __restrict__ ctx16) {
    int t = blockIdx.x, b = blockIdx.y;
    int d = threadIdx.x;
    __shared__ float ps[HH][256];
    #pragma unroll
    for (int it = 0; it < 4; it++) {
        int e = threadIdx.x + it * 512;
        int hh = e >> 8, ss2 = e & 255;
        ps[hh][ss2] = probs[(((size_t)b * HH + hh) * TT + t) * 256 + ss2];
    }
    __syncthreads();
    int h = d >> 6;
    float acc = 0;
    for (int s = 0; s < 256; s++)
        acc += ps[h][s] * vbuf[((size_t)b * 256 + s) * DD + d];
    ctx16[((size_t)b * TT + t) * DD + d] = __float2bfloat16(acc);
}

// =========================================================================
// LayerNorm (biased var, eps 1e-5); writes fp32 + optional bf16
// =========================================================================
__global__ __launch_bounds__(256) void ln_k(const float* __restrict__ in,
                                            const float* __restrict__ g,
                                            const float* __restrict__ bt,
                                            float* __restrict__ out,
                                            bf16* __restrict__ out16) {
    int row = blockIdx.x;
    const float* x = in + (size_t)row * DD;
    int i0 = threadIdx.x, i1 = threadIdx.x + 256;
    float v0 = x[i0], v1 = x[i1];
    __shared__ float red[256];
    red[i0] = v0 + v1; __syncthreads();
    for (int off = 128; off > 0; off >>= 1) {
        if (i0 < off) red[i0] += red[i0 + off];
        __syncthreads();
    }
    float mu = red[0] * (1.0f / DD); __syncthreads();
    float d0 = v0 - mu, d1 = v1 - mu;
    red[i0] = d0 * d0 + d1 * d1; __syncthreads();
    for (int off = 128; off > 0; off >>= 1) {
        if (i0 < off) red[i0] += red[i0 + off];
        __syncthreads();
    }
    float rstd = rsqrtf(red[0] * (1.0f / DD) + 1e-5f);
    float g0 = g ? g[i0] : 1.f, g1 = g ? g[i1] : 1.f;
    float b0 = bt ? bt[i0] : 0.f, b1 = bt ? bt[i1] : 0.f;
    size_t o = (size_t)row * DD;
    float r0 = d0 * rstd * g0 + b0, r1 = d1 * rstd * g1 + b1;
    out[o + i0] = r0; out[o + i1] = r1;
    if (out16) {
        out16[o + i0] = __float2bfloat16(r0);
        out16[o + i1] = __float2bfloat16(r1);
    }
}

// =========================================================================
// host orchestration
// =========================================================================
static inline void g_launch(const bf16* A, const bf16* Bt, const float* bias,
                            const float* res, float* Cf, bf16* Ch,
                            int M, int N, int K, int lda, int relu,
                            hipStream_t stream) {
    gemm_bf16_k<<<dim3(N / 64, M / 128), 256, 0, stream>>>(A, Bt, bias, res, Cf, Ch,
                                                           M, N, K, lda, relu);
}

extern "C" void kernel_launch(void* const* d_in, const int* in_sizes, int n_in,
                              void* d_out, int out_size, void* d_ws, size_t ws_size,
                              hipStream_t stream) {
    const int*   dec_inputs  = (const int*)  d_in[0];
    const int*   enc_inputs  = (const int*)  d_in[1];
    const float* enc_outputs = (const float*)d_in[2];
    const float* ast_outputs = (const float*)d_in[3];
    const float* src_embed   = (const float*)d_in[4];
    const float* ast_embed   = (const float*)d_in[5];
    const float* emb         = (const float*)d_in[7];
    const float* attn_W      = (const float*)d_in[8];
    const float* attn_ln_g   = (const float*)d_in[9];
    const float* attn_ln_b   = (const float*)d_in[10];
    const float* ffn_W1      = (const float*)d_in[11];
    const float* ffn_W2      = (const float*)d_in[12];
    const float* conv_w      = (const float*)d_in[13];
    const float* conv_b      = (const float*)d_in[14];
    const float* multi_ffn_W = (const float*)d_in[15];
    const float* multi_ffn_b = (const float*)d_in[16];

    const size_t NTD = (size_t)BB * TT * DD;        // 2,097,152
    const size_t ATT = (size_t)BB * HH * TT * 256;  // 8,388,608

    float* out_x    = (float*)d_out;
    float* out_self = out_x + NTD;
    float* out_enc  = out_self + (size_t)LL * ATT;
    float* out_ast  = out_enc + (size_t)LL * ATT;

    // ---- workspace bump allocator (256B aligned) ----
    char* wp = (char*)d_ws;
    auto alloc = [&](size_t bytes) { char* r = wp; wp += (bytes + 255) & ~(size_t)255; return (void*)r; };
    float* xb    = (float*)alloc(NTD * 4);
    float* tmp   = (float*)alloc(NTD * 4);
    float* qb    = (float*)alloc(NTD * 4);
    float* kb    = (float*)alloc(NTD * 4);
    float* vb    = (float*)alloc(NTD * 4);
    float* ast1  = (float*)alloc(NTD * 4);
    float* mmctx = (float*)alloc(NTD * 4);
    bf16* xb16   = (bf16*)alloc(NTD * 2);
    bf16* enc16  = (bf16*)alloc(NTD * 2);
    bf16* mo16   = (bf16*)alloc(NTD * 2);
    bf16* cb16   = (bf16*)alloc(NTD * 2);
    bf16* hb16   = (bf16*)alloc((size_t)BB * TT * DFF * 2);
    bf16* acat   = (bf16*)alloc(NTD * 2 * 2);                        // [4096,1024]
    bf16* Wt_attn  = (bf16*)alloc((size_t)72 * DD * DD * 2);
    bf16* Wt_ffn1  = (bf16*)alloc((size_t)LL * DD * DFF * 2);        // [2048,512] x6
    bf16* Wt_ffn2  = (bf16*)alloc((size_t)LL * DFF * DD * 2);        // [512,2048] x6
    bf16* Wt_multi = (bf16*)alloc((size_t)2 * DD * DD * 2);          // [512,1024]

    const int M = BB * TT;  // 4096

    // ---- one-time (per call) weight transposes + input converts ----
    transp_k<<<dim3(16, 16, 72), 256, 0, stream>>>(attn_W, Wt_attn, DD, DD);
    transp_k<<<dim3(64, 16, LL), 256, 0, stream>>>(ffn_W1, Wt_ffn1, DD, DFF);
    transp_k<<<dim3(16, 64, LL), 256, 0, stream>>>(ffn_W2, Wt_ffn2, DFF, DD);
    transp_k<<<dim3(16, 32, 1), 256, 0, stream>>>(multi_ffn_W, Wt_multi, 2 * DD, DD);
    cvt_k<<<NTD / 1024, 256, 0, stream>>>(enc_outputs, enc16);
    cat_src_k<<<M, 256, 0, stream>>>(src_embed, acat);

    // ---- embedding + PE ----
    embed_k<<<M, 256, 0, stream>>>(dec_inputs, emb, xb, xb16);

    // ---- Multi_model front-end ----
    conv_k<<<dim3(SS, BB), 256, 0, stream>>>(ast_outputs, ast_embed, conv_w, conv_b,
                                             ast1, acat);
    mm_attn_k<<<dim3(SS, BB), 256, 0, stream>>>(ast1, enc_outputs, mmctx);
    // multi_out = cat(src,ast_e1) @ multi_ffn_W + b + mm_ctx  (bf16 out only)
    g_launch(acat, Wt_multi, multi_ffn_b, mmctx, nullptr, mo16,
             M, DD, 2 * DD, 2 * DD, 0, stream);

    // ---- decoder layers ----
    for (int l = 0; l < LL; l++) {
        for (int a = 0; a < 3; a++) {
            const bf16* Wq = Wt_attn + (size_t)((l * 3 + a) * 4 + 0) * DD * DD;
            const bf16* Wk = Wt_attn + (size_t)((l * 3 + a) * 4 + 1) * DD * DD;
            const bf16* Wv = Wt_attn + (size_t)((l * 3 + a) * 4 + 2) * DD * DD;
            const bf16* Wo = Wt_attn + (size_t)((l * 3 + a) * 4 + 3) * DD * DD;
            const float* g  = attn_ln_g + ((size_t)l * 3 + a) * DD;
            const float* be = attn_ln_b + ((size_t)l * 3 + a) * DD;
            const bf16* kvsrc = (a == 0) ? xb16 : (a == 1) ? enc16 : mo16;
            float* probs = ((a == 0) ? out_self : (a == 1) ? out_enc : out_ast) + (size_t)l * ATT;
            int mode = (a == 0) ? 0 : (a == 1) ? 1 : 2;
            const int* ids = (a == 0) ? dec_inputs : enc_inputs;

            g_launch(xb16,  Wq, nullptr, nullptr, qb, nullptr, M, DD, DD, DD, 0, stream);
            g_launch(kvsrc, Wk, nullptr, nullptr, kb, nullptr, M, DD, DD, DD, 0, stream);
            g_launch(kvsrc, Wv, nullptr, nullptr, vb, nullptr, M, DD, DD, DD, 0, stream);
            attn_scores_k<<<dim3(TT, HH, BB), 256, 0, stream>>>(qb, kb, ids, probs, mode);
            attn_ctx_k<<<dim3(TT, BB), 512, 0, stream>>>(probs, vb, cb16);
            g_launch(cb16, Wo, nullptr, xb, tmp, nullptr, M, DD, DD, DD, 0, stream);
            ln_k<<<M, 256, 0, stream>>>(tmp, g, be, xb, xb16);
        }
        // FFN
        g_launch(xb16, Wt_ffn1 + (size_t)l * DD * DFF, nullptr, nullptr,
                 nullptr, hb16, M, DFF, DD, DD, 1 /*relu*/, stream);
        g_launch(hb16, Wt_ffn2 + (size_t)l * DFF * DD, nullptr, xb,
                 tmp, nullptr, M, DD, DFF, DFF, 0, stream);
        float* xdst = (l == LL - 1) ? out_x : xb;
        ln_k<<<M, 256, 0, stream>>>(tmp, nullptr, nullptr, xdst,
                                    (l == LL - 1) ? nullptr : xb16);
    }
}